// Round 9
// baseline (458.144 us; speedup 1.0000x reference)
//
#include <hip/hip_runtime.h>

#define NN 100000
#define FIN 128
#define HD 32
#define EE 3200000
#define NBUK 391            // coarse buckets of 256 nodes
#define EPB 6144            // edges per binning chunk (LDS-sort fits in 64KB)
#define NBLK ((EE + EPB - 1) / EPB)   // 521

typedef unsigned int uint;
typedef unsigned short ushort;

__device__ __forceinline__ ushort f2bf(float f) {
    uint b = __float_as_uint(f);
    return (ushort)((b + 0x7FFFu + ((b >> 16) & 1u)) >> 16);
}
__device__ __forceinline__ float bf2f(ushort u) {
    return __uint_as_float(((uint)u) << 16);
}

// ---- per-wave self-detect of edge_index dtype (int64 -> odd dwords all 0) ----
__device__ __forceinline__ int detect64(const uint* __restrict__ ei32) {
    int l = threadIdx.x & 63;
    uint v = 0;
#pragma unroll
    for (int r = 0; r < 4; r++) v |= ei32[2 * (l + 64 * r) + 1];
    return (__ballot(v != 0u) == 0ULL) ? 1 : 0;
}

// values < 2^31 and non-negative: for int64, low dword suffices
__device__ __forceinline__ int load_idx32(const int* __restrict__ ei, long long pos, int is64) {
    return is64 ? ei[pos * 2] : ei[pos];
}

// ---------------- passA: coarse histogram (LDS atomics only) ----------------
__global__ __launch_bounds__(256) void passA_hist(const int* __restrict__ ei,
                                                  int* __restrict__ blockhist) {
    __shared__ int hist[NBUK];
    int tid = threadIdx.x, blk = blockIdx.x;
    int is64 = detect64((const uint*)ei);
    for (int b = tid; b < NBUK; b += 256) hist[b] = 0;
    __syncthreads();
    int e0 = blk * EPB, e1 = e0 + EPB; if (e1 > EE) e1 = EE;
    for (int e = e0 + tid; e < e1; e += 256) {
        int col = load_idx32(ei, (long long)EE + e, is64);
        atomicAdd(&hist[col >> 8], 1);
    }
    __syncthreads();
    for (int b = tid; b < NBUK; b += 256) blockhist[blk * NBUK + b] = hist[b];
}

// ---------------- per-bucket exclusive scan over chunks ----------------
__global__ void scan_bucket(const int* __restrict__ blockhist, int* __restrict__ off_local,
                            int* __restrict__ total) {
    int b = blockIdx.x;          // bucket
    int l = threadIdx.x;         // 0..63 (one wave)
    int run = 0;
    for (int c = 0; c < NBLK; c += 64) {
        int blk = c + l;
        int v = (blk < NBLK) ? blockhist[blk * NBUK + b] : 0;
        int incl = v;
#pragma unroll
        for (int d = 1; d < 64; d <<= 1) {
            int t = __shfl_up(incl, d, 64);
            if (l >= d) incl += t;
        }
        if (blk < NBLK) off_local[blk * NBUK + b] = run + (incl - v);
        run += __shfl(incl, 63, 64);
    }
    if (l == 0) total[b] = run;
}

__global__ void scan_total(const int* __restrict__ total, int* __restrict__ bstart) {
    __shared__ int sd[512];
    int t = threadIdx.x;
    int v = (t < NBUK) ? total[t] : 0;
    sd[t] = v;
    __syncthreads();
    for (int off = 1; off < 512; off <<= 1) {
        int x = (t >= off) ? sd[t - off] : 0;
        __syncthreads();
        sd[t] += x;
        __syncthreads();
    }
    if (t < NBUK) bstart[t] = sd[t] - v;
    if (t == NBUK - 1) bstart[NBUK] = sd[t];
}

// ---------------- sortC: LDS-sorted chunk scatter (coalesced writes) --------
// rec = {row17 | bf15(wt)<<17, col32}
__global__ __launch_bounds__(256) void sortC_kernel(const int* __restrict__ ei,
                                                    const float* __restrict__ wt,
                                                    const int* __restrict__ bstart,
                                                    const int* __restrict__ off_local,
                                                    const int* __restrict__ blockhist,
                                                    uint2* __restrict__ erec2) {
    __shared__ uint2 lrec[EPB];      // 49152 B
    __shared__ int lstart[NBUK];
    __shared__ int lcur[NBUK];
    int tid = threadIdx.x, blk = blockIdx.x;
    int is64 = detect64((const uint*)ei);
    if (tid < 64) {                  // wave 0: exclusive scan of this chunk's hist
        int run = 0;
        for (int c = 0; c < NBUK; c += 64) {
            int b = c + tid;
            int v = (b < NBUK) ? blockhist[blk * NBUK + b] : 0;
            int incl = v;
#pragma unroll
            for (int d = 1; d < 64; d <<= 1) {
                int t2 = __shfl_up(incl, d, 64);
                if (tid >= d) incl += t2;
            }
            if (b < NBUK) { lstart[b] = run + incl - v; lcur[b] = run + incl - v; }
            run += __shfl(incl, 63, 64);
        }
    }
    __syncthreads();
    int e0 = blk * EPB, e1 = e0 + EPB; if (e1 > EE) e1 = EE;
    for (int e = e0 + tid; e < e1; e += 256) {
        int row = load_idx32(ei, e, is64);
        int col = load_idx32(ei, (long long)EE + e, is64);
        uint nb = __float_as_uint(wt[e]);
        uint enc = ((nb + 0x8000u) >> 16) & 0x7FFFu;   // bf16 round, drop sign(=0)
        int pos = atomicAdd(&lcur[col >> 8], 1);       // LDS atomic
        uint2 r; r.x = (uint)row | (enc << 17); r.y = (uint)col;
        lrec[pos] = r;
    }
    __syncthreads();
    int m = e1 - e0;
    for (int slot = tid; slot < m; slot += 256) {
        uint2 r = lrec[slot];
        int b = (int)(r.y >> 8);
        int gpos = bstart[b] + off_local[blk * NBUK + b] + (slot - lstart[b]);
        erec2[gpos] = r;             // contiguous within each bucket segment
    }
}

// ------- passB: per-bucket fine sort + dinv + degree-bin bases (fused) -------
__global__ __launch_bounds__(256) void passB_fine(const uint2* __restrict__ erec2,
                                                  const int* __restrict__ bstart,
                                                  uint* __restrict__ erecF,
                                                  int* __restrict__ estart, int* __restrict__ cnt,
                                                  float* __restrict__ dinv,
                                                  int* __restrict__ degCnt,
                                                  int* __restrict__ blockBase) {
    __shared__ int hist[256];
    __shared__ float wsum[256];
    __shared__ int off[256];
    __shared__ int cur[256];
    __shared__ int sd[256];
    __shared__ int dh[128];
    int t = threadIdx.x, b = blockIdx.x;
    hist[t] = 0; wsum[t] = 0.f;
    if (t < 128) dh[t] = 0;
    __syncthreads();
    int e0 = bstart[b], e1 = bstart[b + 1];
    for (int e = e0 + t; e < e1; e += 256) {
        uint2 r = erec2[e];
        int cl = (int)(r.y & 255u);
        atomicAdd(&hist[cl], 1);
        atomicAdd(&wsum[cl], __uint_as_float((r.x >> 17) << 16));
    }
    __syncthreads();
    int v = hist[t];
    sd[t] = v;
    __syncthreads();
    for (int o = 1; o < 256; o <<= 1) {
        int x = (t >= o) ? sd[t - o] : 0;
        __syncthreads();
        sd[t] += x;
        __syncthreads();
    }
    off[t] = sd[t] - v;
    cur[t] = 0;
    int node = b * 256 + t;
    if (node < NN) {
        estart[node] = e0 + off[t];
        cnt[node] = v;
        dinv[node] = rsqrtf(1.0f + wsum[t]);   // 1 = self-loop weight
        int bin = v < 127 ? v : 127;
        atomicAdd(&dh[bin], 1);                // degree histogram for balance sort
    }
    __syncthreads();
    if (t < 128) {
        int c = dh[t];
        blockBase[b * 128 + t] = c ? atomicAdd(&degCnt[t], c) : 0;  // base within bin
    }
    for (int e = e0 + t; e < e1; e += 256) {
        uint2 r = erec2[e];
        int cl = (int)(r.y & 255u);
        int p = atomicAdd(&cur[cl], 1);        // LDS atomic
        erecF[e0 + off[cl] + p] = r.x;         // dense per-node-sorted
    }
}

// ------- scanD: exclusive scan of degree bins in DESCENDING order (LPT) -------
__global__ void scanD_kernel(const int* __restrict__ degCnt, int* __restrict__ binStart) {
    __shared__ int sd[128];
    int t = threadIdx.x;             // 128 threads
    int v = degCnt[127 - t];
    sd[t] = v;
    __syncthreads();
    for (int off = 1; off < 128; off <<= 1) {
        int x = (t >= off) ? sd[t - off] : 0;
        __syncthreads();
        sd[t] += x;
        __syncthreads();
    }
    binStart[127 - t] = sd[t] - v;
}

// ------- permscatter: perm sorted by degree descending ----------------------
__global__ __launch_bounds__(256) void permscatter_kernel(const int* __restrict__ cnt,
                                                          const int* __restrict__ binStart,
                                                          const int* __restrict__ blockBase,
                                                          int* __restrict__ perm) {
    __shared__ int cur[128];
    int t = threadIdx.x, b = blockIdx.x;
    if (t < 128) cur[t] = 0;
    __syncthreads();
    int node = b * 256 + t;
    if (node < NN) {
        int v = cnt[node];
        int bin = v < 127 ? v : 127;
        int r = atomicAdd(&cur[bin], 1);
        perm[binStart[bin] + blockBase[b * 128 + bin] + r] = node;
    }
}

// ---------------- fixup: fold dinv[row] into record weight ----------------
__global__ void fixup_kernel(uint* __restrict__ erecF, const float* __restrict__ dinv) {
    int e = blockIdx.x * blockDim.x + threadIdx.x;
    if (e >= EE) return;
    uint v = erecF[e];
    int row = (int)(v & 0x1FFFFu);
    float w = __uint_as_float((v >> 17) << 16);
    float wd = w * dinv[row];                  // < 1 always, sign 0
    uint nb = __float_as_uint(wd);
    uint enc = ((nb + 0x8000u) >> 16) & 0x7FFFu;
    erecF[e] = (uint)row | (enc << 17);
}

// ---------------- xw = x @ [Wc_z | Wc_r | Wc_h]  (f32 VALU, bf16 output) -------
// Output layout per node (96 ushort): [z0,r0, z1,r1, ..., z31,r31, h0..h31]
__global__ __launch_bounds__(256) void gemm_xw_kernel(
        const float* __restrict__ x,
        const float* __restrict__ Wz, const float* __restrict__ Wr, const float* __restrict__ Wh,
        ushort* __restrict__ xw16) {
    __shared__ float Bs[128 * 96];   // Bs[k*96 + c], k GLOBAL (0..127)
    __shared__ float AsT[8 * 128];   // AsT[kk*128 + row], kk local (0..7)
    int tid = threadIdx.x;
    int tx = tid & 31, ty = tid >> 5;
    int rowBase = blockIdx.x * 128;

    for (int e = tid; e < 4096; e += 256) { int k = e >> 5, c = e & 31; Bs[k * 96 + c]      = Wz[e]; }
    for (int e = tid; e < 4096; e += 256) { int k = e >> 5, c = e & 31; Bs[k * 96 + 32 + c] = Wr[e]; }
    for (int e = tid; e < 4096; e += 256) { int k = e >> 5, c = e & 31; Bs[k * 96 + 64 + c] = Wh[e]; }

    float acc0[16], acc1[16], acc2[16];
#pragma unroll
    for (int r = 0; r < 16; r++) { acc0[r] = 0.f; acc1[r] = 0.f; acc2[r] = 0.f; }

    int lr = tid >> 1;
    int lc = (tid & 1) * 4;
    for (int k0 = 0; k0 < 128; k0 += 8) {
        __syncthreads();
        int gr = rowBase + lr;
        float4 a4 = make_float4(0.f, 0.f, 0.f, 0.f);
        if (gr < NN) a4 = *(const float4*)(x + (long long)gr * FIN + k0 + lc);
        AsT[(lc + 0) * 128 + lr] = a4.x;
        AsT[(lc + 1) * 128 + lr] = a4.y;
        AsT[(lc + 2) * 128 + lr] = a4.z;
        AsT[(lc + 3) * 128 + lr] = a4.w;
        __syncthreads();
#pragma unroll
        for (int kk = 0; kk < 8; kk++) {
            float b0 = Bs[(k0 + kk) * 96 + tx];
            float b1 = Bs[(k0 + kk) * 96 + 32 + tx];
            float b2 = Bs[(k0 + kk) * 96 + 64 + tx];
            const float4* ap = (const float4*)(AsT + kk * 128 + ty * 16);
            float4 a0 = ap[0], a1 = ap[1], a2 = ap[2], a3 = ap[3];
            float av[16] = {a0.x,a0.y,a0.z,a0.w, a1.x,a1.y,a1.z,a1.w,
                            a2.x,a2.y,a2.z,a2.w, a3.x,a3.y,a3.z,a3.w};
#pragma unroll
            for (int r = 0; r < 16; r++) {
                acc0[r] = fmaf(av[r], b0, acc0[r]);
                acc1[r] = fmaf(av[r], b1, acc1[r]);
                acc2[r] = fmaf(av[r], b2, acc2[r]);
            }
        }
    }
#pragma unroll
    for (int r = 0; r < 16; r++) {
        int gr = rowBase + ty * 16 + r;
        if (gr < NN) {
            ushort* o = xw16 + (long long)gr * 96;
            uint zr = (uint)f2bf(acc0[r]) | ((uint)f2bf(acc1[r]) << 16);
            *(uint*)(o + 2 * tx) = zr;      // 4B coalesced
            o[64 + tx] = f2bf(acc2[r]);     // 2B
        }
    }
}

// ---------------- fused gather-aggregate + GRU gates + head ----------------
// Nodes assigned via degree-descending perm: all 16 groups in a block (and both
// groups of each wave64) have near-equal degree -> no max-of-16 barrier tax.
__global__ __launch_bounds__(512) void agg_gate_kernel(
        const uint* __restrict__ erecF, const int* __restrict__ estart, const int* __restrict__ cnt,
        const int* __restrict__ perm,
        const ushort* __restrict__ xw16, const float* __restrict__ dinv,
        const float* __restrict__ hprev,
        const float* __restrict__ bcz, const float* __restrict__ bcr, const float* __restrict__ bch,
        const float* __restrict__ Wlz, const float* __restrict__ blz,
        const float* __restrict__ Wlr, const float* __restrict__ blr,
        const float* __restrict__ Wlh, const float* __restrict__ blh,
        const float* __restrict__ Whead, const float* __restrict__ bhead,
        float* __restrict__ y, float* __restrict__ hnew) {
    __shared__ float WzT[64 * 32], WrT[64 * 32], WhT[64 * 32];  // WT[k*32+j] = Wl[j*64+k]
    __shared__ float czs[16][32], crs[16][32], chs[16][32], hps[16][32], rhs[16][32];
    __shared__ uint rwsh[16][32];   // staged records per group
    int tid = threadIdx.x;
    for (int e2 = tid; e2 < 2048; e2 += 512) {
        int jj = e2 >> 6, k = e2 & 63;
        WzT[k * 32 + jj] = Wlz[e2];
        WrT[k * 32 + jj] = Wlr[e2];
        WhT[k * 32 + jj] = Wlh[e2];
    }
    int s = tid >> 5, j = tid & 31;
    int i = perm[blockIdx.x * 16 + s];
    int beg = estart[i], c = cnt[i], end = beg + c;

    float cz = 0.f, cr = 0.f, ch = 0.f;
    int e = beg + j;
    uint vcur = (e < end) ? erecF[e] : 0u;      // batch 0
    for (int base = beg; base < end; base += 32) {
        rwsh[s][j] = vcur;                      // in-order DS within wave: safe
        int en = base + 32 + j;
        uint vnext = (en < end) ? erecF[en] : 0u;   // prefetch next batch
        int mm = end - base; if (mm > 32) mm = 32;
        int t = 0;
        for (; t + 4 <= mm; t += 4) {
            uint v0 = rwsh[s][t], v1 = rwsh[s][t + 1], v2 = rwsh[s][t + 2], v3 = rwsh[s][t + 3];
            const ushort* p0 = xw16 + (long long)(v0 & 0x1FFFFu) * 96;
            const ushort* p1 = xw16 + (long long)(v1 & 0x1FFFFu) * 96;
            const ushort* p2 = xw16 + (long long)(v2 & 0x1FFFFu) * 96;
            const ushort* p3 = xw16 + (long long)(v3 & 0x1FFFFu) * 96;
            uint a0 = *(const uint*)(p0 + 2 * j);
            uint a1 = *(const uint*)(p1 + 2 * j);
            uint a2 = *(const uint*)(p2 + 2 * j);
            uint a3 = *(const uint*)(p3 + 2 * j);
            ushort h0 = p0[64 + j], h1 = p1[64 + j], h2 = p2[64 + j], h3 = p3[64 + j];
            float w0 = __uint_as_float((v0 >> 17) << 16);
            float w1 = __uint_as_float((v1 >> 17) << 16);
            float w2 = __uint_as_float((v2 >> 17) << 16);
            float w3 = __uint_as_float((v3 >> 17) << 16);
            cz = fmaf(w0, __uint_as_float(a0 << 16), cz);
            cr = fmaf(w0, __uint_as_float(a0 & 0xFFFF0000u), cr);
            ch = fmaf(w0, bf2f(h0), ch);
            cz = fmaf(w1, __uint_as_float(a1 << 16), cz);
            cr = fmaf(w1, __uint_as_float(a1 & 0xFFFF0000u), cr);
            ch = fmaf(w1, bf2f(h1), ch);
            cz = fmaf(w2, __uint_as_float(a2 << 16), cz);
            cr = fmaf(w2, __uint_as_float(a2 & 0xFFFF0000u), cr);
            ch = fmaf(w2, bf2f(h2), ch);
            cz = fmaf(w3, __uint_as_float(a3 << 16), cz);
            cr = fmaf(w3, __uint_as_float(a3 & 0xFFFF0000u), cr);
            ch = fmaf(w3, bf2f(h3), ch);
        }
        for (; t < mm; t++) {
            uint v = rwsh[s][t];
            const ushort* xr = xw16 + (long long)(v & 0x1FFFFu) * 96;
            uint zr = *(const uint*)(xr + 2 * j);
            float fh = bf2f(xr[64 + j]);
            float w = __uint_as_float((v >> 17) << 16);
            cz = fmaf(w, __uint_as_float(zr << 16), cz);
            cr = fmaf(w, __uint_as_float(zr & 0xFFFF0000u), cr);
            ch = fmaf(w, fh, ch);
        }
        vcur = vnext;
    }
    // apply dinv[col] factor; self-loop (norm = dinv^2) + bias
    float di = dinv[i], sl = di * di;
    const ushort* xi = xw16 + (long long)i * 96;
    uint zri = *(const uint*)(xi + 2 * j);
    czs[s][j] = fmaf(sl, __uint_as_float(zri << 16),         di * cz) + bcz[j];
    crs[s][j] = fmaf(sl, __uint_as_float(zri & 0xFFFF0000u), di * cr) + bcr[j];
    chs[s][j] = fmaf(sl, bf2f(xi[64 + j]),                   di * ch) + bch[j];
    float hp = hprev[(long long)i * HD + j];
    hps[s][j] = hp;
    __syncthreads();

    float az = blz[j], arv = blr[j];
#pragma unroll
    for (int k = 0; k < 32; k++) {
        az  = fmaf(WzT[k * 32 + j], czs[s][k], az);
        arv = fmaf(WrT[k * 32 + j], crs[s][k], arv);
    }
#pragma unroll
    for (int k = 0; k < 32; k++) {
        float v = hps[s][k];
        az  = fmaf(WzT[(k + 32) * 32 + j], v, az);
        arv = fmaf(WrT[(k + 32) * 32 + j], v, arv);
    }
    float Z = 1.f / (1.f + __expf(-az));
    float R = 1.f / (1.f + __expf(-arv));
    rhs[s][j] = hp * R;
    __syncthreads();

    float ah = blh[j];
#pragma unroll
    for (int k = 0; k < 32; k++) ah = fmaf(WhT[k * 32 + j], chs[s][k], ah);
#pragma unroll
    for (int k = 0; k < 32; k++) ah = fmaf(WhT[(k + 32) * 32 + j], rhs[s][k], ah);
    float Ht = tanhf(ah);
    float hn = Z * hp + (1.f - Z) * Ht;
    float yv = fmaxf(hn, 0.f) * Whead[j];
#pragma unroll
    for (int m = 16; m; m >>= 1) yv += __shfl_xor(yv, m, 32);
    hnew[(long long)i * HD + j] = hn;
    if (j == 0) y[i] = yv + bhead[0];
}

extern "C" void kernel_launch(void* const* d_in, const int* in_sizes, int n_in,
                              void* d_out, int out_size, void* d_ws, size_t ws_size,
                              hipStream_t stream) {
    const float* x     = (const float*)d_in[0];
    const int*   ei    = (const int*)d_in[1];
    const float* wt    = (const float*)d_in[2];
    const float* hprev = (const float*)d_in[3];
    const float* Wcz = (const float*)d_in[4],  *bcz = (const float*)d_in[5];
    const float* Wlz = (const float*)d_in[6],  *blz = (const float*)d_in[7];
    const float* Wcr = (const float*)d_in[8],  *bcr = (const float*)d_in[9];
    const float* Wlr = (const float*)d_in[10], *blr = (const float*)d_in[11];
    const float* Wch = (const float*)d_in[12], *bch = (const float*)d_in[13];
    const float* Wlh = (const float*)d_in[14], *blh = (const float*)d_in[15];
    const float* Whead = (const float*)d_in[16], *bhead = (const float*)d_in[17];

    float* out_y = (float*)d_out;            // [N]
    float* out_h = (float*)d_out + NN;       // [N,32]

    float* ws = (float*)d_ws;
    float* dinv      = ws;                                    // NN f32
    int*   estart    = (int*)(ws + NN);                       // NN
    int*   cnt       = (int*)(ws + 2LL * NN);                 // NN
    int*   perm      = (int*)(ws + 3LL * NN);                 // NN
    int*   bstart    = (int*)(ws + 4LL * NN);                 // NBUK+1 (pad 512)
    int*   total     = (int*)(ws + 4LL * NN + 512);           // NBUK (pad 512)
    int*   degCnt    = (int*)(ws + 4LL * NN + 1024);          // 128 (pad 512)
    int*   binStart  = (int*)(ws + 4LL * NN + 1536);          // 128 (pad 512)
    int*   blockhist = (int*)(ws + 4LL * NN + 2048);          // NBLK*NBUK=203711 (pad 204000)
    int*   off_local = (int*)(ws + 4LL * NN + 206048);        // 203711 (pad 204000)
    int*   blockBase = (int*)(ws + 4LL * NN + 410048);        // NBUK*128=50048 (pad 50176)
    ushort* xw16     = (ushort*)(ws + 4LL * NN + 460224);     // 96*NN ushort (= 48NN f32)
    uint2*  erec2    = (uint2*)(ws + 52LL * NN + 460224);     // EE uint2 (even offset: 8B-aligned)
    uint*   erecF    = (uint*)(ws + 52LL * NN + 460224 + 2LL * EE);  // EE uint

    hipMemsetAsync(degCnt, 0, 128 * sizeof(int), stream);
    passA_hist<<<NBLK, 256, 0, stream>>>(ei, blockhist);
    scan_bucket<<<NBUK, 64, 0, stream>>>(blockhist, off_local, total);
    scan_total<<<1, 512, 0, stream>>>(total, bstart);
    sortC_kernel<<<NBLK, 256, 0, stream>>>(ei, wt, bstart, off_local, blockhist, erec2);
    passB_fine<<<NBUK, 256, 0, stream>>>(erec2, bstart, erecF, estart, cnt, dinv, degCnt, blockBase);
    scanD_kernel<<<1, 128, 0, stream>>>(degCnt, binStart);
    permscatter_kernel<<<NBUK, 256, 0, stream>>>(cnt, binStart, blockBase, perm);
    gemm_xw_kernel<<<(NN + 127) / 128, 256, 0, stream>>>(x, Wcz, Wcr, Wch, xw16);
    fixup_kernel<<<(EE + 255) / 256, 256, 0, stream>>>(erecF, dinv);
    agg_gate_kernel<<<NN / 16, 512, 0, stream>>>(
        erecF, estart, cnt, perm, xw16, dinv, hprev, bcz, bcr, bch,
        Wlz, blz, Wlr, blr, Wlh, blh, Whead, bhead, out_y, out_h);
}